// Round 2
// baseline (9240.661 us; speedup 1.0000x reference)
//
#include <hip/hip_runtime.h>
#include <math.h>

#define H 128
#define W 128
#define NB 8
#define NFC 64
#define OC4 432  // DG*3*KK = 16*3*9

// ---------------------------------------------------------------------------
// backwarp: one thread per (n,y,x), loop over 64 channels
// ---------------------------------------------------------------------------
__global__ __launch_bounds__(256) void k_backwarp(
    const float* __restrict__ nbr, const float* __restrict__ flow,
    float* __restrict__ out)
{
    int idx = blockIdx.x * 256 + threadIdx.x;   // n*H*W + y*W + x
    int x = idx & (W - 1);
    int y = (idx >> 7) & (H - 1);
    int n = idx >> 14;

    float fx = flow[((n * 2 + 0) * H + y) * W + x];
    float fy = flow[((n * 2 + 1) * H + y) * W + x];
    float px = (float)x + fx;
    float py = (float)y + fy;
    float x0f = floorf(px), y0f = floorf(py);
    int x0 = (int)x0f, y0 = (int)y0f;
    float dx = px - x0f, dy = py - y0f;

    float vy0 = (y0 >= 0 && y0 < H) ? 1.f : 0.f;
    float vy1 = (y0 + 1 >= 0 && y0 + 1 < H) ? 1.f : 0.f;
    float vx0 = (x0 >= 0 && x0 < W) ? 1.f : 0.f;
    float vx1 = (x0 + 1 >= 0 && x0 + 1 < W) ? 1.f : 0.f;
    float w00 = (1.f - dy) * (1.f - dx) * vy0 * vx0;
    float w01 = (1.f - dy) * dx * vy0 * vx1;
    float w10 = dy * (1.f - dx) * vy1 * vx0;
    float w11 = dy * dx * vy1 * vx1;

    int y0c = min(max(y0, 0), H - 1);
    int y1c = min(max(y0 + 1, 0), H - 1);
    int x0c = min(max(x0, 0), W - 1);
    int x1c = min(max(x0 + 1, 0), W - 1);
    int o00 = y0c * W + x0c, o01 = y0c * W + x1c;
    int o10 = y1c * W + x0c, o11 = y1c * W + x1c;

    const float* base = nbr + (size_t)n * NFC * H * W;
    float* ob = out + (size_t)n * NFC * H * W + y * W + x;
    for (int c = 0; c < NFC; ++c) {
        const float* fp = base + c * (H * W);
        float v = w00 * fp[o00] + w01 * fp[o01] + w10 * fp[o10] + w11 * fp[o11];
        ob[c * (H * W)] = v;
    }
}

// ---------------------------------------------------------------------------
// conv3x3 + lrelu, OC=64. 8x8 pixel tile per 256-thread block.
// thread = (oc = tid&63, quarter q = tid>>6 -> 4x4 pixels)
// IC = 64 or 128 (concat of in0,in1)
// ---------------------------------------------------------------------------
template <int IC>
__global__ __launch_bounds__(256) void k_conv3x3(
    const float* __restrict__ in0, const float* __restrict__ in1,
    const float* __restrict__ wgt, const float* __restrict__ bias,
    float* __restrict__ out)
{
    __shared__ float inbuf[IC * 100];   // [ic][10][10]
    __shared__ float wbuf[64 * 37];     // [oc][4ic x 9] pitch 37

    int bid = blockIdx.x;
    int tx = bid & 15, ty = (bid >> 4) & 15, n = bid >> 8;
    int bx = tx * 8, by = ty * 8;
    int tid = threadIdx.x;
    int oc = tid & 63;
    int q = tid >> 6;
    int qy = (q >> 1) * 4, qx = (q & 1) * 4;

    for (int idx = tid; idx < IC * 100; idx += 256) {
        int ic = idx / 100;
        int r = idx - ic * 100;
        int iy = by + r / 10 - 1;
        int ix = bx + (r % 10) - 1;
        float v = 0.f;
        if (iy >= 0 && iy < H && ix >= 0 && ix < W) {
            const float* src;
            int c;
            if (IC == 64 || ic < 64) { src = in0; c = ic; }
            else                     { src = in1; c = ic - 64; }
            v = src[((n * NFC + c) * H + iy) * W + ix];
        }
        inbuf[idx] = v;
    }

    float acc[4][4] = {};
    for (int icc = 0; icc < IC / 4; ++icc) {
        __syncthreads();
        for (int idx = tid; idx < 64 * 36; idx += 256) {
            int o = idx / 36;
            int r = idx - o * 36;
            wbuf[o * 37 + r] = wgt[(o * IC + icc * 4) * 9 + r];
        }
        __syncthreads();
        for (int i = 0; i < 4; ++i) {
            int ic = icc * 4 + i;
            float rv[6][6];
            const float* ib = &inbuf[ic * 100 + qy * 10 + qx];
            #pragma unroll
            for (int r = 0; r < 6; ++r)
                #pragma unroll
                for (int c = 0; c < 6; ++c)
                    rv[r][c] = ib[r * 10 + c];
            #pragma unroll
            for (int k = 0; k < 9; ++k) {
                float w = wbuf[oc * 37 + i * 9 + k];
                int ky = k / 3, kx = k % 3;
                #pragma unroll
                for (int py = 0; py < 4; ++py)
                    #pragma unroll
                    for (int pxx = 0; pxx < 4; ++pxx)
                        acc[py][pxx] += w * rv[py + ky][pxx + kx];
            }
        }
    }

    float b = bias[oc];
    for (int py = 0; py < 4; ++py) {
        int yy = by + qy + py;
        float4 v;
        float* vv = &v.x;
        #pragma unroll
        for (int pxx = 0; pxx < 4; ++pxx) {
            float t = acc[py][pxx] + b;
            vv[pxx] = t >= 0.f ? t : 0.1f * t;
        }
        *(float4*)&out[((size_t)(n * NFC + oc) * H + yy) * W + bx + qx] = v;
    }
}

// ---------------------------------------------------------------------------
// fused conv4 (64->432) + offset/mask transform + DCNv2 + lrelu
// 4x4 pixel tile per 256-thread block.
// ---------------------------------------------------------------------------
__global__ __launch_bounds__(256) void k_conv4_dcn(
    const float* __restrict__ h3, const float* __restrict__ w4,
    const float* __restrict__ b4, const float* __restrict__ nbr,
    const float* __restrict__ flow, const float* __restrict__ dcw,
    const float* __restrict__ dcb, float* __restrict__ out)
{
    __shared__ float c432[16 * 433];   // [px][ch], pitch 433
    __shared__ float wbuf[64 * 37];    // weight staging, pitch 37
    __shared__ float s_pool[16 * 577]; // phase1: inbuf [64][6][6] (2304); phase2: samp [px][577]

    int bid = blockIdx.x;
    int tx = bid & 31, ty = (bid >> 5) & 31, n = bid >> 10;
    int bx = tx * 4, by = ty * 4;
    int tid = threadIdx.x;
    int oc = tid & 63;
    int row = tid >> 6;   // 0..3 (pixel row within tile for phase1/3)

    // ---- stage h3 tile 6x6 x 64ch into s_pool ----
    for (int idx = tid; idx < 64 * 36; idx += 256) {
        int ic = idx / 36;
        int r = idx - ic * 36;
        int iy = by + r / 6 - 1;
        int ix = bx + (r % 6) - 1;
        float v = 0.f;
        if (iy >= 0 && iy < H && ix >= 0 && ix < W)
            v = h3[((n * NFC + ic) * H + iy) * W + ix];
        s_pool[idx] = v;
    }

    // ---- phase 1: conv4 into c432 LDS ----
    for (int occ = 0; occ < 7; ++occ) {
        int ochan = occ * 64 + oc;
        float acc[4] = {0.f, 0.f, 0.f, 0.f};
        for (int icc = 0; icc < 16; ++icc) {
            __syncthreads();
            for (int idx = tid; idx < 64 * 36; idx += 256) {
                int o = idx / 36;
                int r = idx - o * 36;
                int och = occ * 64 + o;
                wbuf[o * 37 + r] = (och < OC4) ? w4[(och * 64 + icc * 4) * 9 + r] : 0.f;
            }
            __syncthreads();
            for (int i = 0; i < 4; ++i) {
                int ic = icc * 4 + i;
                float rv[3][6];
                const float* ib = &s_pool[ic * 36 + row * 6];
                #pragma unroll
                for (int r = 0; r < 3; ++r)
                    #pragma unroll
                    for (int c = 0; c < 6; ++c)
                        rv[r][c] = ib[r * 6 + c];
                #pragma unroll
                for (int k = 0; k < 9; ++k) {
                    float w = wbuf[oc * 37 + i * 9 + k];
                    int ky = k / 3, kx = k % 3;
                    #pragma unroll
                    for (int c = 0; c < 4; ++c)
                        acc[c] += w * rv[ky][c + kx];
                }
            }
        }
        if (ochan < OC4) {
            float b = b4[ochan];
            #pragma unroll
            for (int c = 0; c < 4; ++c)
                c432[(row * 4 + c) * 433 + ochan] = acc[c] + b;
        }
    }
    __syncthreads();

    // ---- phase 2: deformable sampling into samp (s_pool) ----
    {
        int spx = tid >> 4;       // pixel 0..15
        int ss = tid & 15;
        int pyi = by + (spx >> 2);
        int pxi = bx + (spx & 3);
        float f_x = flow[((n * 2 + 0) * H + pyi) * W + pxi];
        float f_y = flow[((n * 2 + 1) * H + pyi) * W + pxi];
        const float* cp = &c432[spx * 433];
        const float* nbase = nbr + (size_t)n * NFC * H * W;
        for (int j = ss; j < 576; j += 16) {
            int g = j / 36;
            int r = j - g * 36;
            int c = r / 9;
            int k = r - c * 9;
            int gk = g * 9 + k;
            float dyv = f_y + cp[2 * gk];
            float dxv = f_x + cp[2 * gk + 1];
            float m = 1.f / (1.f + expf(-cp[288 + gk]));
            float sy = (float)(pyi + (k / 3) - 1) + dyv;
            float sx = (float)(pxi + (k % 3) - 1) + dxv;

            float y0f = floorf(sy), x0f = floorf(sx);
            int y0 = (int)y0f, x0 = (int)x0f;
            float ddy = sy - y0f, ddx = sx - x0f;
            float vy0 = (y0 >= 0 && y0 < H) ? 1.f : 0.f;
            float vy1 = (y0 + 1 >= 0 && y0 + 1 < H) ? 1.f : 0.f;
            float vx0 = (x0 >= 0 && x0 < W) ? 1.f : 0.f;
            float vx1 = (x0 + 1 >= 0 && x0 + 1 < W) ? 1.f : 0.f;
            float w00 = (1.f - ddy) * (1.f - ddx) * vy0 * vx0;
            float w01 = (1.f - ddy) * ddx * vy0 * vx1;
            float w10 = ddy * (1.f - ddx) * vy1 * vx0;
            float w11 = ddy * ddx * vy1 * vx1;
            int y0c = min(max(y0, 0), H - 1);
            int y1c = min(max(y0 + 1, 0), H - 1);
            int x0c = min(max(x0, 0), W - 1);
            int x1c = min(max(x0 + 1, 0), W - 1);
            const float* fp = nbase + (size_t)(g * 4 + c) * H * W;
            float v = w00 * fp[y0c * W + x0c] + w01 * fp[y0c * W + x1c] +
                      w10 * fp[y1c * W + x0c] + w11 * fp[y1c * W + x1c];
            s_pool[spx * 577 + j] = v * m;
        }
    }
    __syncthreads();

    // ---- phase 3: einsum out[oc] = sum_j samp[px][j] * dcw[oc][j] ----
    float accO[4] = {0.f, 0.f, 0.f, 0.f};
    for (int jc = 0; jc < 16; ++jc) {
        __syncthreads();
        for (int idx = tid; idx < 64 * 36; idx += 256) {
            int o = idx / 36;
            int r = idx - o * 36;
            wbuf[o * 37 + r] = dcw[o * 576 + jc * 36 + r];
        }
        __syncthreads();
        #pragma unroll
        for (int r = 0; r < 36; ++r) {
            float w = wbuf[oc * 37 + r];
            int j = jc * 36 + r;
            #pragma unroll
            for (int c2 = 0; c2 < 4; ++c2)
                accO[c2] += w * s_pool[(row * 4 + c2) * 577 + j];
        }
    }
    float bb = dcb[oc];
    float4 vo;
    float* vv = &vo.x;
    #pragma unroll
    for (int c2 = 0; c2 < 4; ++c2) {
        float t = accO[c2] + bb;
        vv[c2] = t >= 0.f ? t : 0.1f * t;
    }
    *(float4*)&out[((size_t)(n * NFC + oc) * H + by + row) * W + bx] = vo;
}

// ---------------------------------------------------------------------------
extern "C" void kernel_launch(void* const* d_in, const int* in_sizes, int n_in,
                              void* d_out, int out_size, void* d_ws, size_t ws_size,
                              hipStream_t stream)
{
    const float* nbr  = (const float*)d_in[0];
    const float* ref  = (const float*)d_in[1];
    const float* flow = (const float*)d_in[2];
    const float* w1   = (const float*)d_in[3];
    const float* b1   = (const float*)d_in[4];
    const float* w2   = (const float*)d_in[5];
    const float* b2   = (const float*)d_in[6];
    const float* w3   = (const float*)d_in[7];
    const float* b3   = (const float*)d_in[8];
    const float* w4   = (const float*)d_in[9];
    const float* b4   = (const float*)d_in[10];
    const float* dcw  = (const float*)d_in[11];
    const float* dcb  = (const float*)d_in[12];
    float* out = (float*)d_out;
    float* ws = (float*)d_ws;

    const size_t FEAT = (size_t)NB * NFC * H * W;   // 8388608 floats
    float* warped = ws;
    float* h1 = ws + FEAT;
    float* h2 = ws + 2 * FEAT;
    float* h3 = warped;  // reuse: warped dead after conv1

    k_backwarp<<<NB * H * W / 256, 256, 0, stream>>>(nbr, flow, warped);
    k_conv3x3<128><<<NB * 256, 256, 0, stream>>>(warped, ref, w1, b1, h1);
    k_conv3x3<64><<<NB * 256, 256, 0, stream>>>(h1, nullptr, w2, b2, h2);
    k_conv3x3<64><<<NB * 256, 256, 0, stream>>>(h2, nullptr, w3, b3, h3);
    k_conv4_dcn<<<NB * 1024, 256, 0, stream>>>(h3, w4, b4, nbr, flow, dcw, dcb, out);
}

// Round 3
// 458.773 us; speedup vs baseline: 20.1421x; 20.1421x over previous
//
#include <hip/hip_runtime.h>
#include <math.h>

#define H 128
#define W 128
#define NB 8
#define NFC 64

typedef __attribute__((ext_vector_type(8))) short s16x8;
typedef __attribute__((ext_vector_type(4))) short s16x4;
typedef __attribute__((ext_vector_type(4))) float f32x4;
typedef __attribute__((ext_vector_type(4))) int   i32x4;

__device__ __forceinline__ float b2f(short s) {
    return __uint_as_float(((unsigned)(unsigned short)s) << 16);
}
__device__ __forceinline__ short f2bf(float f) {
    unsigned u = __float_as_uint(f);
    u += 0x7FFF + ((u >> 16) & 1);
    return (short)(u >> 16);
}
__device__ __forceinline__ short f2h(float f) {
    _Float16 h = (_Float16)f;
    return __builtin_bit_cast(short, h);
}
__device__ __forceinline__ float h2f(short s) {
    return (float)__builtin_bit_cast(_Float16, s);
}

// ---------------------------------------------------------------------------
// weight transform: w fp32 [OC][IC][3][3] -> wT bf16 [OCpad][9][64]
// grid covers OCpad*576 threads; zero-pad oc >= OC.
// ---------------------------------------------------------------------------
__global__ __launch_bounds__(256) void k_wt(const float* __restrict__ w,
                                            short* __restrict__ wT,
                                            int OC, int IC, int icoff)
{
    int idx = blockIdx.x * 256 + threadIdx.x;
    int o = idx / 576;
    int r = idx - o * 576;
    int t = r >> 6, i = r & 63;
    float v = (o < OC) ? w[((size_t)o * IC + icoff + i) * 9 + t] : 0.f;
    wT[idx] = f2bf(v);
}

// ---------------------------------------------------------------------------
// NCHW fp32 -> NHWC bf16
// ---------------------------------------------------------------------------
__global__ __launch_bounds__(256) void k_nhwc(const float* __restrict__ src,
                                              short* __restrict__ dst)
{
    int px = blockIdx.x * 256 + threadIdx.x;   // (n,y,x)
    int n = px >> 14;
    int sp = px & 16383;
    const float* s = src + (size_t)n * 64 * 16384 + sp;
    unsigned pk[32];
    #pragma unroll
    for (int c = 0; c < 32; ++c) {
        float v0 = s[(size_t)(2 * c) * 16384];
        float v1 = s[(size_t)(2 * c + 1) * 16384];
        pk[c] = (unsigned)(unsigned short)f2bf(v0) |
                ((unsigned)(unsigned short)f2bf(v1) << 16);
    }
    i32x4* d = (i32x4*)(dst + (size_t)px * 64);
    #pragma unroll
    for (int qq = 0; qq < 8; ++qq) {
        i32x4 t;
        t[0] = pk[4 * qq]; t[1] = pk[4 * qq + 1];
        t[2] = pk[4 * qq + 2]; t[3] = pk[4 * qq + 3];
        d[qq] = t;
    }
}

// ---------------------------------------------------------------------------
// backwarp: nbrH (NHWC bf16) + flow -> warped (NHWC bf16)
// thread = (pixel, 16-channel quarter)
// ---------------------------------------------------------------------------
__global__ __launch_bounds__(256) void k_backwarp(const short* __restrict__ nbrH,
                                                  const float* __restrict__ flow,
                                                  short* __restrict__ warped)
{
    int idx = blockIdx.x * 256 + threadIdx.x;
    int px = idx >> 2, qt = idx & 3;
    int n = px >> 14;
    int x = px & 127, y = (px >> 7) & 127;
    float fx = flow[(size_t)(n * 2 + 0) * 16384 + y * 128 + x];
    float fy = flow[(size_t)(n * 2 + 1) * 16384 + y * 128 + x];
    float pxf = (float)x + fx, pyf = (float)y + fy;
    float x0f = floorf(pxf), y0f = floorf(pyf);
    int x0 = (int)x0f, y0 = (int)y0f;
    float dx = pxf - x0f, dy = pyf - y0f;
    float vy0 = ((unsigned)y0 < 128u) ? 1.f : 0.f;
    float vy1 = ((unsigned)(y0 + 1) < 128u) ? 1.f : 0.f;
    float vx0 = ((unsigned)x0 < 128u) ? 1.f : 0.f;
    float vx1 = ((unsigned)(x0 + 1) < 128u) ? 1.f : 0.f;
    float w00 = (1.f - dy) * (1.f - dx) * vy0 * vx0;
    float w01 = (1.f - dy) * dx * vy0 * vx1;
    float w10 = dy * (1.f - dx) * vy1 * vx0;
    float w11 = dy * dx * vy1 * vx1;
    int y0c = min(max(y0, 0), 127), y1c = min(max(y0 + 1, 0), 127);
    int x0c = min(max(x0, 0), 127), x1c = min(max(x0 + 1, 0), 127);
    const short* nb = nbrH + (size_t)n * 16384 * 64 + qt * 16;
    const short* p00 = nb + (y0c * 128 + x0c) * 64;
    const short* p01 = nb + (y0c * 128 + x1c) * 64;
    const short* p10 = nb + (y1c * 128 + x0c) * 64;
    const short* p11 = nb + (y1c * 128 + x1c) * 64;
    s16x8 a00 = *(const s16x8*)p00, b00 = *(const s16x8*)(p00 + 8);
    s16x8 a01 = *(const s16x8*)p01, b01 = *(const s16x8*)(p01 + 8);
    s16x8 a10 = *(const s16x8*)p10, b10 = *(const s16x8*)(p10 + 8);
    s16x8 a11 = *(const s16x8*)p11, b11 = *(const s16x8*)(p11 + 8);
    s16x8 r0, r1;
    #pragma unroll
    for (int c = 0; c < 8; ++c) {
        float v = w00 * b2f(a00[c]) + w01 * b2f(a01[c]) + w10 * b2f(a10[c]) + w11 * b2f(a11[c]);
        r0[c] = f2bf(v);
        float u = w00 * b2f(b00[c]) + w01 * b2f(b01[c]) + w10 * b2f(b10[c]) + w11 * b2f(b11[c]);
        r1[c] = f2bf(u);
    }
    short* o = warped + (size_t)px * 64 + qt * 16;
    *(s16x8*)o = r0;
    *(s16x8*)(o + 8) = r1;
}

// ---------------------------------------------------------------------------
// MFMA conv3x3, IC=64. Block = 128 px (16w x 8h), 4 waves.
// Wave: 64oc x 32px (4 M-tiles x 2 N-patches), K = 9 taps x 64 ic.
// MODE 0: store fp32 partial (no bias/act)
// MODE 1: + partial + bias + lrelu -> bf16
// MODE 2: + bias + lrelu -> bf16
// MODE 3: conv4 epilogue: + bias, flow-add/sigmoid -> fp16 offmask (og=blockIdx.y)
// ---------------------------------------------------------------------------
template<int MODE>
__global__ __launch_bounds__(256) void k_conv(
    const short* __restrict__ in, const short* __restrict__ wT,
    const float* __restrict__ bias,
    float* __restrict__ partial, short* __restrict__ outB,
    short* __restrict__ offmask, const float* __restrict__ flow, int n0)
{
    __shared__ __align__(16) short tileS[180 * 64];  // 23040 B, swizzled NHWC halo tile
    __shared__ __align__(16) short aS[64 * 64];      // 8192 B, swizzled weight chunk

    int tid = threadIdx.x;
    int bid = blockIdx.x;
    int og = (MODE == 3) ? blockIdx.y : 0;
    int n  = (MODE == 3) ? (n0 + (bid >> 7)) : (bid >> 7);
    int tl = bid & 127;
    int bx = (tl & 7) << 4;
    int by = (tl >> 3) << 3;
    int ln = tid & 63, wv = tid >> 6;
    int c = ln & 15, q = ln >> 4;

    // stage input tile: rows by-1..by+8 (10), cols bx-1..bx+16 (18)
    for (int i = tid; i < 1440; i += 256) {
        int pt = i >> 3, c16 = i & 7;
        int ty = pt / 18, tx = pt - ty * 18;
        int gy = by + ty - 1, gx = bx + tx - 1;
        i32x4 v = {0, 0, 0, 0};
        if ((unsigned)gy < 128u && (unsigned)gx < 128u)
            v = *(const i32x4*)(in + (((size_t)n * 128 + gy) * 128 + gx) * 64 + c16 * 8);
        *(i32x4*)((char*)tileS + pt * 128 + ((c16 ^ (pt & 7)) << 4)) = v;
    }

    const short* wbase = wT + (size_t)og * 64 * 576;
    int aoc = tid >> 3, ac8 = tid & 7;
    i32x4 sa0, sa1;
    // preload tap 0 weights
    sa0 = *(const i32x4*)(wbase + (size_t)aoc * 576 + ac8 * 8);
    sa1 = *(const i32x4*)(wbase + (size_t)(aoc + 32) * 576 + ac8 * 8);

    f32x4 acc[4][2];
    #pragma unroll
    for (int m = 0; m < 4; ++m) {
        acc[m][0] = (f32x4){0.f, 0.f, 0.f, 0.f};
        acc[m][1] = (f32x4){0.f, 0.f, 0.f, 0.f};
    }

    int p0 = 2 * wv, p1 = 2 * wv + 1;
    int pby0 = (p0 >> 2) << 2, pbx0 = (p0 & 3) << 2;
    int pby1 = (p1 >> 2) << 2, pbx1 = (p1 & 3) << 2;
    int cy = c >> 2, cx = c & 3;

    __syncthreads();  // tile ready

    for (int tap = 0; tap < 9; ++tap) {
        // write staged weight chunk
        *(i32x4*)((char*)aS + aoc * 128 + ((ac8 ^ (aoc & 7)) << 4)) = sa0;
        *(i32x4*)((char*)aS + (aoc + 32) * 128 + ((ac8 ^ ((aoc + 32) & 7)) << 4)) = sa1;
        // issue next tap's loads early (hide under compute)
        if (tap < 8) {
            sa0 = *(const i32x4*)(wbase + (size_t)aoc * 576 + (tap + 1) * 64 + ac8 * 8);
            sa1 = *(const i32x4*)(wbase + (size_t)(aoc + 32) * 576 + (tap + 1) * 64 + ac8 * 8);
        }
        __syncthreads();  // aS ready

        int dty = tap / 3, dtx = tap - dty * 3;
        int pta = (pby0 + cy + dty) * 18 + pbx0 + cx + dtx;
        int ptb = (pby1 + cy + dty) * 18 + pbx1 + cx + dtx;
        #pragma unroll
        for (int ih = 0; ih < 2; ++ih) {
            int slot = ih * 4 + q;
            s16x8 bf0 = *(const s16x8*)((const char*)tileS + pta * 128 + ((slot ^ (pta & 7)) << 4));
            s16x8 bf1 = *(const s16x8*)((const char*)tileS + ptb * 128 + ((slot ^ (ptb & 7)) << 4));
            #pragma unroll
            for (int m = 0; m < 4; ++m) {
                int ocl = m * 16 + c;
                s16x8 a = *(const s16x8*)((const char*)aS + ocl * 128 + ((slot ^ (ocl & 7)) << 4));
                acc[m][0] = __builtin_amdgcn_mfma_f32_16x16x32_bf16(a, bf0, acc[m][0], 0, 0, 0);
                acc[m][1] = __builtin_amdgcn_mfma_f32_16x16x32_bf16(a, bf1, acc[m][1], 0, 0, 0);
            }
        }
        __syncthreads();  // done reading aS
    }

    // epilogue
    #pragma unroll
    for (int p = 0; p < 2; ++p) {
        int pby = p ? pby1 : pby0;
        int pbx = p ? pbx1 : pbx0;
        int y = by + pby + cy;
        int x = bx + pbx + cx;
        size_t pxi = ((size_t)n * 128 + y) * 128 + x;
        float fy = 0.f, fx2 = 0.f;
        if (MODE == 3) {
            fy  = flow[(size_t)(n * 2 + 1) * 16384 + y * 128 + x];
            fx2 = flow[(size_t)(n * 2 + 0) * 16384 + y * 128 + x];
        }
        #pragma unroll
        for (int m = 0; m < 4; ++m) {
            int o0 = m * 16 + q * 4;
            f32x4 v = acc[m][p];
            if (MODE == 0) {
                *(f32x4*)(partial + pxi * 64 + o0) = v;
            } else if (MODE == 1 || MODE == 2) {
                f32x4 bv = *(const f32x4*)(bias + o0);
                if (MODE == 1) {
                    f32x4 pv = *(const f32x4*)(partial + pxi * 64 + o0);
                    v += pv;
                }
                v += bv;
                s16x4 r;
                #pragma unroll
                for (int j = 0; j < 4; ++j) {
                    float t = v[j];
                    t = t >= 0.f ? t : 0.1f * t;
                    r[j] = f2bf(t);
                }
                *(s16x4*)(outB + pxi * 64 + o0) = r;
            } else {  // MODE 3
                int oc4 = og * 64 + o0;
                if (oc4 < 432) {
                    f32x4 bv = *(const f32x4*)(bias + oc4);
                    v += bv;
                    s16x4 r;
                    if (oc4 < 288) {
                        v[0] += fy; v[1] += fx2; v[2] += fy; v[3] += fx2;
                        #pragma unroll
                        for (int j = 0; j < 4; ++j) r[j] = f2h(v[j]);
                    } else {
                        #pragma unroll
                        for (int j = 0; j < 4; ++j) r[j] = f2h(1.f / (1.f + expf(-v[j])));
                    }
                    size_t nrel = (size_t)(bid >> 7);
                    *(s16x4*)(offmask + (nrel * 16384 + y * 128 + x) * 432 + oc4) = r;
                }
            }
        }
    }
}

// ---------------------------------------------------------------------------
// DCN: barrier-free. Wave = one 4x4 pixel patch. Samples -> B-frags in regs,
// dcwT A-frags direct from global (L2-hot), MFMA einsum, lrelu -> NCHW out.
// ---------------------------------------------------------------------------
__global__ __launch_bounds__(256) void k_dcn(
    const short* __restrict__ offmask, const short* __restrict__ nbrH,
    const short* __restrict__ dcwT, const float* __restrict__ dcb,
    float* __restrict__ out, int n0)
{
    int tid = threadIdx.x;
    int ln = tid & 63, wv = tid >> 6;
    int patch = blockIdx.x * 4 + wv;
    int nrel = patch >> 10;
    int pl = patch & 1023;
    int by = (pl >> 5) << 2, bx = (pl & 31) << 2;
    int n = n0 + nrel;
    int c = ln & 15, q = ln >> 4;
    int y = by + (c >> 2), x = bx + (c & 3);
    const short* om = offmask + ((size_t)nrel * 16384 + y * 128 + x) * 432;
    const short* nb = nbrH + (size_t)n * 16384 * 64;

    s16x8 bfrag[18];
    #pragma unroll
    for (int tap = 0; tap < 9; ++tap) {
        int dty = tap / 3 - 1, dtx = tap - (tap / 3) * 3 - 1;
        #pragma unroll
        for (int ih = 0; ih < 2; ++ih) {
            int ic0 = ih * 32 + q * 8;
            s16x8 bf;
            #pragma unroll
            for (int hh = 0; hh < 2; ++hh) {
                int g = (ic0 >> 2) + hh;
                int gk = g * 9 + tap;
                int dd = *(const int*)(om + 2 * gk);
                float dyv = h2f((short)(dd & 0xffff));
                float dxv = h2f((short)(dd >> 16));
                float mk  = h2f(om[288 + gk]);
                float sy = (float)(y + dty) + dyv;
                float sx = (float)(x + dtx) + dxv;
                float y0f = floorf(sy), x0f = floorf(sx);
                int y0 = (int)y0f, x0 = (int)x0f;
                float ddy = sy - y0f, ddx = sx - x0f;
                float vy0 = ((unsigned)y0 < 128u) ? 1.f : 0.f;
                float vy1 = ((unsigned)(y0 + 1) < 128u) ? 1.f : 0.f;
                float vx0 = ((unsigned)x0 < 128u) ? 1.f : 0.f;
                float vx1 = ((unsigned)(x0 + 1) < 128u) ? 1.f : 0.f;
                float w00 = (1.f - ddy) * (1.f - ddx) * vy0 * vx0;
                float w01 = (1.f - ddy) * ddx * vy0 * vx1;
                float w10 = ddy * (1.f - ddx) * vy1 * vx0;
                float w11 = ddy * ddx * vy1 * vx1;
                int y0c = min(max(y0, 0), 127), y1c = min(max(y0 + 1, 0), 127);
                int x0c = min(max(x0, 0), 127), x1c = min(max(x0 + 1, 0), 127);
                s16x4 v00 = *(const s16x4*)(nb + (y0c * 128 + x0c) * 64 + g * 4);
                s16x4 v01 = *(const s16x4*)(nb + (y0c * 128 + x1c) * 64 + g * 4);
                s16x4 v10 = *(const s16x4*)(nb + (y1c * 128 + x0c) * 64 + g * 4);
                s16x4 v11 = *(const s16x4*)(nb + (y1c * 128 + x1c) * 64 + g * 4);
                #pragma unroll
                for (int cc = 0; cc < 4; ++cc) {
                    float sv = w00 * b2f(v00[cc]) + w01 * b2f(v01[cc]) +
                               w10 * b2f(v10[cc]) + w11 * b2f(v11[cc]);
                    bf[hh * 4 + cc] = f2bf(sv * mk);
                }
            }
            bfrag[tap * 2 + ih] = bf;
        }
    }

    f32x4 acc[4];
    #pragma unroll
    for (int m = 0; m < 4; ++m) acc[m] = (f32x4){0.f, 0.f, 0.f, 0.f};
    #pragma unroll
    for (int kc = 0; kc < 18; ++kc) {
        int tap = kc >> 1, ih = kc & 1;
        int ic0 = ih * 32 + q * 8;
        #pragma unroll
        for (int m = 0; m < 4; ++m) {
            s16x8 a = *(const s16x8*)(dcwT + ((size_t)(m * 16 + c) * 9 + tap) * 64 + ic0);
            acc[m] = __builtin_amdgcn_mfma_f32_16x16x32_bf16(a, bfrag[kc], acc[m], 0, 0, 0);
        }
    }
    #pragma unroll
    for (int m = 0; m < 4; ++m) {
        int o0 = m * 16 + q * 4;
        f32x4 bv = *(const f32x4*)(dcb + o0);
        f32x4 v = acc[m] + bv;
        #pragma unroll
        for (int j = 0; j < 4; ++j) {
            float t = v[j];
            t = t >= 0.f ? t : 0.1f * t;
            out[((size_t)n * 64 + o0 + j) * 16384 + y * 128 + x] = t;
        }
    }
}

// ---------------------------------------------------------------------------
extern "C" void kernel_launch(void* const* d_in, const int* in_sizes, int n_in,
                              void* d_out, int out_size, void* d_ws, size_t ws_size,
                              hipStream_t stream)
{
    const float* nbr  = (const float*)d_in[0];
    const float* ref  = (const float*)d_in[1];
    const float* flow = (const float*)d_in[2];
    const float* w1   = (const float*)d_in[3];
    const float* b1   = (const float*)d_in[4];
    const float* w2   = (const float*)d_in[5];
    const float* b2   = (const float*)d_in[6];
    const float* w3   = (const float*)d_in[7];
    const float* b3   = (const float*)d_in[8];
    const float* w4   = (const float*)d_in[9];
    const float* b4   = (const float*)d_in[10];
    const float* dcw  = (const float*)d_in[11];
    const float* dcb  = (const float*)d_in[12];
    float* out = (float*)d_out;
    char* ws = (char*)d_ws;

    // ws layout (bytes):
    // [0        , 16.78M): warped -> h1          (later: offmask low half)
    // [16.78M   , 33.55M): refH   -> h2          (later: offmask high half)
    // [33.55M   , 67.11M): h1p (fp32)  -> h3 (bf16, first 16.78M)
    // [67.11M   , 83.89M): nbrH
    // [83.89M   , ~84.8M): wT pool
    short* warped_h1 = (short*)ws;
    short* refH_h2   = (short*)(ws + 16777216);
    float* h1p       = (float*)(ws + 33554432);
    short* h3        = (short*)(ws + 33554432);
    short* nbrH      = (short*)(ws + 67108864);
    short* wpool     = (short*)(ws + 83886080);
    short* wT1a = wpool;
    short* wT1b = wpool + 36864;
    short* wT2  = wpool + 73728;
    short* wT3  = wpool + 110592;
    short* wT4  = wpool + 147456;   // 448*576
    short* dcwT = wpool + 405504;
    short* offmask = (short*)ws;    // 2 images * 16384 * 432 fp16 = 28.3 MB

    // weight transforms
    k_wt<<<144, 256, 0, stream>>>(w1, wT1a, 64, 128, 0);
    k_wt<<<144, 256, 0, stream>>>(w1, wT1b, 64, 128, 64);
    k_wt<<<144, 256, 0, stream>>>(w2, wT2, 64, 64, 0);
    k_wt<<<144, 256, 0, stream>>>(w3, wT3, 64, 64, 0);
    k_wt<<<1008, 256, 0, stream>>>(w4, wT4, 432, 64, 0);
    k_wt<<<144, 256, 0, stream>>>(dcw, dcwT, 64, 64, 0);

    // layout conversions
    k_nhwc<<<512, 256, 0, stream>>>(nbr, nbrH);
    k_nhwc<<<512, 256, 0, stream>>>(ref, refH_h2);

    // backwarp -> warped (NHWC bf16)
    k_backwarp<<<2048, 256, 0, stream>>>(nbrH, flow, warped_h1);

    // conv1 as two IC-64 passes
    k_conv<0><<<1024, 256, 0, stream>>>(warped_h1, wT1a, nullptr, h1p, nullptr, nullptr, nullptr, 0);
    k_conv<1><<<1024, 256, 0, stream>>>(refH_h2, wT1b, b1, h1p, warped_h1, nullptr, nullptr, 0);
    // conv2: h1 -> h2
    k_conv<2><<<1024, 256, 0, stream>>>(warped_h1, wT2, b2, nullptr, refH_h2, nullptr, nullptr, 0);
    // conv3: h2 -> h3
    k_conv<2><<<1024, 256, 0, stream>>>(refH_h2, wT3, b3, nullptr, h3, nullptr, nullptr, 0);

    // conv4 + DCN in 2-image quarters
    for (int n0 = 0; n0 < 8; n0 += 2) {
        dim3 g4(256, 7);
        k_conv<3><<<g4, 256, 0, stream>>>(h3, wT4, b4, nullptr, nullptr, offmask, flow, n0);
        k_dcn<<<512, 256, 0, stream>>>(offmask, nbrH, dcwT, dcb, out, n0);
    }
}